// Round 4
// baseline (509.798 us; speedup 1.0000x reference)
//
#include <hip/hip_runtime.h>
#include <hip/hip_bf16.h>

// VoxelGrid: 10M events -> (10, 720, 1280) fp32 grid, bilinear splat in time.
// R1: naive 20M device atomics -> 21 G atomics/s ceiling (958 us).
// R2: row-bucket sort (p2) + per-row LDS accumulate (p3) = 467 us.
// R3: 64B-aligned runs halved WRITE_SIZE (250->126MB) but dur unchanged ->
//     p2 is LATENCY-bound at 22% occupancy (128 blocks = half the CUs idle).
// R4: 256 blocks x 1024 thr (16 waves on every CU), non-temporal pass-B event
//     reads (don't evict open L2 write lines), runtime bucket cap from ws_size
//     with exact overflow fallback (direct atomics into memset out; p3 does +=).

#define NUM_BINS 5
#define DT_OFFSET 1
#define GW 1280
#define GH 720
#define NSLAB (NUM_BINS * 2)   // 10 (bin, polarity) slabs
#define NB2 256                // phase-2 blocks (1 per CU, 16 waves each)
#define CURSOR_BYTES 4096

typedef float v4f __attribute__((ext_vector_type(4)));

// ---------------- Phase 2: bucket events by row y ----------------
// Packed word: [q:16 | pos:1 | xi:11], tn ~= q / 65535.
__global__ __launch_bounds__(1024) void p2_bucket(
        const float4* __restrict__ ev, int n,
        unsigned* __restrict__ cursor, unsigned* __restrict__ bucket,
        float* __restrict__ out, int cap,
        const int* __restrict__ ct_p, const int* __restrict__ dt_p) {
    __shared__ unsigned hist[GH];
    __shared__ unsigned base[GH];

    const int chunk = (n + gridDim.x - 1) / gridDim.x;
    const int start = blockIdx.x * chunk;
    const int end   = min(n, start + chunk);

    for (int k = threadIdx.x; k < GH; k += blockDim.x) hist[k] = 0u;
    __syncthreads();

    // pass A: per-row counts (normal loads: seed L3 for pass B's re-read)
    for (int i = start + (int)threadIdx.x; i < end; i += blockDim.x) {
        int yi = (int)ev[i].z;
        atomicAdd(&hist[yi], 1u);
    }
    __syncthreads();

    // reserve 64B-aligned runs; zero pad slots (zero word decodes to +0.0)
    for (int k = threadIdx.x; k < GH; k += blockDim.x) {
        unsigned c = hist[k];
        if (c) {
            unsigned r = (c + 15u) & ~15u;          // round to 16 slots = 64B
            unsigned b = atomicAdd(&cursor[k], r);  // one atomic per (blk,row)
            base[k] = b;
            unsigned* bk = bucket + (size_t)k * cap;
            for (unsigned j = c; j < r; ++j) {
                unsigned slot = b + j;
                if (slot < (unsigned)cap) bk[slot] = 0u;
            }
        } else {
            base[k] = 0u;
        }
        hist[k] = 0u;                               // becomes pass-B cursor
    }
    __syncthreads();

    const int ct  = *ct_p;
    const int dti = *dt_p;
    const float bt  = (float)(ct - dti);
    const float dtf = (float)(dti + DT_OFFSET);

    // pass B: pack + scatter. Non-temporal event reads: the 160MB read stream
    // must not evict the open bucket write lines from the per-XCD L2.
    const v4f* evv = (const v4f*)ev;
    for (int i = start + (int)threadIdx.x; i < end; i += blockDim.x) {
        v4f e = __builtin_nontemporal_load(evv + i);
        int yi  = (int)e.z;
        int xi  = (int)e.y;
        int pos = (e.w > 0.0f) ? 1 : 0;
        float tn = (e.x - bt) / dtf;               // in [0, 1)
        unsigned q = (unsigned)(tn * 65535.0f + 0.5f);
        if (q > 65535u) q = 65535u;
        unsigned word = (q << 12) | ((unsigned)pos << 11) | (unsigned)xi;
        unsigned j    = atomicAdd(&hist[yi], 1u);
        unsigned slot = base[yi] + j;
        if (slot < (unsigned)cap) {
            bucket[(size_t)yi * cap + slot] = word;
        } else {
            // overflow (statistically rare): exact direct splat; out is
            // memset-0 and p3 does += writeout, so this is exact.
            float bf   = (NUM_BINS - 1.0f) * tn;
            float back = floorf(bf);
            float fw   = bf - back;
            int   b    = (int)back;
            atomicAdd(&out[((size_t)(b * 2 + pos) * GH + yi) * GW + xi],
                      (1.0f - fw) * tn);
            atomicAdd(&out[((size_t)((b + 1) * 2 + pos) * GH + yi) * GW + xi],
                      fw * tn);
        }
    }
}

// ---------------- Phase 3: per-row LDS accumulate + (+=) writeout -----------
__global__ __launch_bounds__(1024) void p3_accum(
        const unsigned* __restrict__ cursor, const unsigned* __restrict__ bucket,
        float* __restrict__ out, int cap) {
    __shared__ float tile[NSLAB * GW];   // 51,200 B -> 2 blocks/CU, 32 waves
    const int y = blockIdx.x;

    for (int k = threadIdx.x; k < NSLAB * GW; k += blockDim.x) tile[k] = 0.0f;
    __syncthreads();

    unsigned cnt = cursor[y];
    if (cnt > (unsigned)cap) cnt = (unsigned)cap;
    const unsigned* bk = bucket + (size_t)y * cap;

    for (unsigned j = threadIdx.x; j < cnt; j += blockDim.x) {
        unsigned w = bk[j];
        int   xi  = (int)(w & 0x7FFu);
        int   pos = (int)((w >> 11) & 1u);
        float tn  = (float)(w >> 12) * (1.0f / 65535.0f);
        float bf  = (NUM_BINS - 1.0f) * tn;
        float back = floorf(bf);
        float fw   = bf - back;
        int   b    = (int)back;                     // in [0,3]
        int   idx  = (b * 2 + pos) * GW + xi;
        atomicAdd(&tile[idx],          (1.0f - fw) * tn);   // ds_add_f32
        atomicAdd(&tile[idx + 2 * GW], fw * tn);
    }
    __syncthreads();

    // += writeout (out was memset-0; overflow atomics from p2 already landed)
    for (int k = threadIdx.x; k < NSLAB * GW / 4; k += blockDim.x) {
        int s  = k / (GW / 4);
        int x4 = k % (GW / 4);
        float4* dst = (float4*)(out + ((size_t)s * GH + y) * GW) + x4;
        float4 v = ((const float4*)(tile + s * GW))[x4];
        float4 o = *dst;
        o.x += v.x; o.y += v.y; o.z += v.z; o.w += v.w;
        *dst = o;
    }
}

// ---------------- Fallback: R1 naive atomic kernel (if ws too small) --------
__global__ void voxel_scatter_kernel(const float4* __restrict__ events,
                                     float* __restrict__ out, int n,
                                     const int* __restrict__ ct_p,
                                     const int* __restrict__ dt_p,
                                     const int* __restrict__ w_p,
                                     const int* __restrict__ h_p) {
    int i = blockIdx.x * blockDim.x + threadIdx.x;
    if (i >= n) return;
    const int ct = *ct_p, dti = *dt_p, W = *w_p, H = *h_p;
    const float bt  = (float)(ct - dti);
    const float dtf = (float)(dti + DT_OFFSET);
    float4 e = events[i];
    const float tn    = (e.x - bt) / dtf;
    const float bin_f = (NUM_BINS - 1.0f) * tn;
    const float back  = floorf(bin_f);
    const float fwd_w = bin_f - back;
    const int back_i = (int)back;
    const int pos    = (e.w > 0.0f) ? 1 : 0;
    const int xi = (int)e.y, yi = (int)e.z;
    const int plane = H * W, slab = 2 * plane;
    const int base = (back_i * 2 + pos) * plane + yi * W + xi;
    atomicAdd(&out[base],        (1.0f - fwd_w) * tn);
    atomicAdd(&out[base + slab], fwd_w * tn);
}

extern "C" void kernel_launch(void* const* d_in, const int* in_sizes, int n_in,
                              void* d_out, int out_size, void* d_ws, size_t ws_size,
                              hipStream_t stream) {
    const float4* events = (const float4*)d_in[0];
    const int* curr_time = (const int*)d_in[1];
    const int* delta_t   = (const int*)d_in[2];
    const int* width     = (const int*)d_in[3];
    const int* height    = (const int*)d_in[4];
    float* out = (float*)d_out;
    const int n = in_sizes[0] / 4;

    // runtime bucket capacity: use all of ws (slots of 16 = 64B lines)
    int cap = 0;
    if (ws_size > CURSOR_BYTES)
        cap = (int)(((ws_size - CURSOR_BYTES) / (GH * sizeof(unsigned))) & ~(size_t)15);

    if (cap >= 16384) {
        unsigned* cursor = (unsigned*)d_ws;
        unsigned* bucket = (unsigned*)((char*)d_ws + CURSOR_BYTES);
        hipMemsetAsync(cursor, 0, GH * sizeof(unsigned), stream);
        hipMemsetAsync(out, 0, (size_t)out_size * sizeof(float), stream);
        p2_bucket<<<NB2, 1024, 0, stream>>>(events, n, cursor, bucket,
                                            out, cap, curr_time, delta_t);
        p3_accum<<<GH, 1024, 0, stream>>>(cursor, bucket, out, cap);
    } else {
        hipMemsetAsync(out, 0, (size_t)out_size * sizeof(float), stream);
        const int block = 256;
        const int grid  = (n + block - 1) / block;
        voxel_scatter_kernel<<<grid, block, 0, stream>>>(events, out, n,
                                                         curr_time, delta_t,
                                                         width, height);
    }
}

// Round 5
// 415.159 us; speedup vs baseline: 1.2280x; 1.2280x over previous
//
#include <hip/hip_runtime.h>
#include <hip/hip_bf16.h>

// VoxelGrid: 10M events -> (10, 720, 1280) fp32 grid, bilinear splat in time.
// R1: naive 20M device atomics -> 21 G atomics/s ceiling (958 us).
// R2-R4: row-bucket sort (p2) + per-row LDS accumulate (p3): p2 stuck at
//   ~190 us across ALL launch shapes (512x256 / 128x1024 / 256x1024), incl.
//   half-the-CUs-idle -> not CU/wave/VALU/BW bound. Diagnosis: 10M scattered
//   4B stores into 720 runs/block; tail lines fill slower than the event
//   read stream evicts them from per-XCD L2 -> 4-5x partial-line HBM write
//   amplification (WRITE_SIZE 230MB vs 47MB payload) at ~25% HBM efficiency.
// R5: coarsen buckets 720 -> 240 (key = y/3, y%3 packed into the record).
//   Runs 3x longer -> tail line fills before eviction -> full-line writebacks.
//   p3 stays per-row (51.2KB tile), reads bucket y/3, filters on ylo (L3 eats
//   the 3x re-read). Overflow -> ws side list, drained by p4 AFTER p3, so no
//   37MB out memset and p3 writes non-atomically with full coverage.

#define NUM_BINS 5
#define DT_OFFSET 1
#define GW 1280
#define GH 720
#define NSLAB (NUM_BINS * 2)   // 10 (bin, polarity) slabs
#define NGRP 240               // coarse buckets (y/3)
#define NB2 256                // phase-2 blocks
#define CURSOR_BYTES 4096      // cursor[0..239] buckets, cursor[240] overflow
#define OF_RESERVE (512*1024)  // overflow list reserve at ws tail
#define MIN_CAPG 45056         // required slots/bucket (mean fill ~45.5K+15sig)

// Packed record: [q:16 | ylo:2 | pos:1 | xi:11], tn ~= q/65535, y = 3*g + ylo.
// Zero word decodes to tn=0 -> contributes +0.0 (pad slots are harmless).

// ---------------- Phase 2: bucket events by y/3 ----------------
__global__ __launch_bounds__(1024) void p2_bucket(
        const float4* __restrict__ ev, int n,
        unsigned* __restrict__ cursor, unsigned* __restrict__ bucket,
        unsigned* __restrict__ oflist, int ofcap, int capg,
        const int* __restrict__ ct_p, const int* __restrict__ dt_p) {
    __shared__ unsigned hist[NGRP];
    __shared__ unsigned base[NGRP];

    const int chunk = (n + gridDim.x - 1) / gridDim.x;
    const int start = blockIdx.x * chunk;
    const int end   = min(n, start + chunk);

    if (threadIdx.x < NGRP) hist[threadIdx.x] = 0u;
    __syncthreads();

    // pass A: per-bucket counts (reads warm L3 for pass B)
    for (int i = start + (int)threadIdx.x; i < end; i += blockDim.x) {
        int yi = (int)ev[i].z;
        atomicAdd(&hist[yi / 3], 1u);
    }
    __syncthreads();

    // reserve 64B-aligned runs; zero pad slots
    if (threadIdx.x < NGRP) {
        unsigned k = threadIdx.x;
        unsigned c = hist[k];
        if (c) {
            unsigned r = (c + 15u) & ~15u;
            unsigned b = atomicAdd(&cursor[k], r);
            base[k] = b;
            unsigned* bk = bucket + (size_t)k * capg;
            for (unsigned j = c; j < r; ++j) {
                unsigned slot = b + j;
                if (slot < (unsigned)capg) bk[slot] = 0u;
            }
        } else {
            base[k] = 0u;
        }
        hist[k] = 0u;          // becomes pass-B cursor
    }
    __syncthreads();

    const int ct  = *ct_p;
    const int dti = *dt_p;
    const float bt  = (float)(ct - dti);
    const float dtf = (float)(dti + DT_OFFSET);

    // pass B: pack + scatter (runs are 3x longer than R4 -> tail lines fill
    // fast enough to stay L2-resident until complete -> full-line writebacks)
    for (int i = start + (int)threadIdx.x; i < end; i += blockDim.x) {
        float4 e = ev[i];
        int yi  = (int)e.z;
        int xi  = (int)e.y;
        int pos = (e.w > 0.0f) ? 1 : 0;
        int g   = yi / 3;
        int ylo = yi - 3 * g;
        float tn = (e.x - bt) / dtf;               // in [0, 1)
        unsigned q = (unsigned)(tn * 65535.0f + 0.5f);
        if (q > 65535u) q = 65535u;
        unsigned word = (q << 14) | ((unsigned)ylo << 12)
                      | ((unsigned)pos << 11) | (unsigned)xi;
        unsigned j    = atomicAdd(&hist[g], 1u);
        unsigned slot = base[g] + j;
        if (slot < (unsigned)capg) {
            bucket[(size_t)g * capg + slot] = word;
        } else {
            // statistically ~never: append to overflow list, drained by p4
            unsigned k = atomicAdd(&cursor[NGRP], 1u);
            if (k < (unsigned)ofcap) {
                oflist[2 * k]     = (unsigned)yi;
                oflist[2 * k + 1] = word;
            }
        }
    }
}

// ---------------- Phase 3: per-row LDS accumulate + exclusive writeout ------
__global__ __launch_bounds__(1024) void p3_accum(
        const unsigned* __restrict__ cursor, const unsigned* __restrict__ bucket,
        float* __restrict__ out, int capg) {
    __shared__ float tile[NSLAB * GW];   // 51,200 B -> 2 blocks/CU
    const int y    = blockIdx.x;
    const int g    = y / 3;
    const unsigned tgt = (unsigned)(y - 3 * g);

    for (int k = threadIdx.x; k < NSLAB * GW; k += blockDim.x) tile[k] = 0.0f;
    __syncthreads();

    unsigned cnt = cursor[g];
    if (cnt > (unsigned)capg) cnt = (unsigned)capg;   // rest went to overflow
    // cnt is a multiple of 16 (64B-aligned reservations) -> exact uint4 loop
    const uint4* bk4 = (const uint4*)(bucket + (size_t)g * capg);
    unsigned n4 = cnt / 4;

    for (unsigned j = threadIdx.x; j < n4; j += blockDim.x) {
        uint4 w4 = bk4[j];
        #pragma unroll
        for (int c = 0; c < 4; ++c) {
            unsigned w = (c == 0) ? w4.x : (c == 1) ? w4.y : (c == 2) ? w4.z : w4.w;
            if (((w >> 12) & 3u) != tgt) continue;    // other row in this bucket
            int   xi  = (int)(w & 0x7FFu);
            int   pos = (int)((w >> 11) & 1u);
            float tn  = (float)(w >> 14) * (1.0f / 65535.0f);
            float bf  = (NUM_BINS - 1.0f) * tn;
            float back = floorf(bf);
            float fw   = bf - back;
            int   b    = (int)back;
            if (b > NUM_BINS - 2) b = NUM_BINS - 2;   // safety clamp
            int   idx  = (b * 2 + pos) * GW + xi;
            atomicAdd(&tile[idx],          (1.0f - fw) * tn);   // ds_add_f32
            atomicAdd(&tile[idx + 2 * GW], fw * tn);
        }
    }
    __syncthreads();

    // exclusive coalesced float4 writeout: row y of each of the 10 slabs
    for (int k = threadIdx.x; k < NSLAB * GW / 4; k += blockDim.x) {
        int s  = k / (GW / 4);
        int x4 = k % (GW / 4);
        ((float4*)(out + ((size_t)s * GH + y) * GW))[x4] =
            ((const float4*)(tile + s * GW))[x4];
    }
}

// ---------------- Phase 4: drain overflow list (usually empty) --------------
__global__ void p4_overflow(const unsigned* __restrict__ cursor,
                            const unsigned* __restrict__ oflist, int ofcap,
                            float* __restrict__ out) {
    unsigned nof = cursor[NGRP];
    if (nof > (unsigned)ofcap) nof = (unsigned)ofcap;
    for (unsigned k = blockIdx.x * blockDim.x + threadIdx.x; k < nof;
         k += gridDim.x * blockDim.x) {
        unsigned yi = oflist[2 * k];
        unsigned w  = oflist[2 * k + 1];
        int   xi  = (int)(w & 0x7FFu);
        int   pos = (int)((w >> 11) & 1u);
        float tn  = (float)(w >> 14) * (1.0f / 65535.0f);
        float bf  = (NUM_BINS - 1.0f) * tn;
        float back = floorf(bf);
        float fw   = bf - back;
        int   b    = (int)back;
        if (b > NUM_BINS - 2) b = NUM_BINS - 2;
        atomicAdd(&out[((size_t)(b * 2 + pos) * GH + yi) * GW + xi],
                  (1.0f - fw) * tn);
        atomicAdd(&out[((size_t)((b + 1) * 2 + pos) * GH + yi) * GW + xi],
                  fw * tn);
    }
}

// ---------------- Fallback: R1 naive atomic kernel (if ws too small) --------
__global__ void voxel_scatter_kernel(const float4* __restrict__ events,
                                     float* __restrict__ out, int n,
                                     const int* __restrict__ ct_p,
                                     const int* __restrict__ dt_p,
                                     const int* __restrict__ w_p,
                                     const int* __restrict__ h_p) {
    int i = blockIdx.x * blockDim.x + threadIdx.x;
    if (i >= n) return;
    const int ct = *ct_p, dti = *dt_p, W = *w_p, H = *h_p;
    const float bt  = (float)(ct - dti);
    const float dtf = (float)(dti + DT_OFFSET);
    float4 e = events[i];
    const float tn    = (e.x - bt) / dtf;
    const float bin_f = (NUM_BINS - 1.0f) * tn;
    const float back  = floorf(bin_f);
    const float fwd_w = bin_f - back;
    const int back_i = (int)back;
    const int pos    = (e.w > 0.0f) ? 1 : 0;
    const int xi = (int)e.y, yi = (int)e.z;
    const int plane = H * W, slab = 2 * plane;
    const int base = (back_i * 2 + pos) * plane + yi * W + xi;
    atomicAdd(&out[base],        (1.0f - fwd_w) * tn);
    atomicAdd(&out[base + slab], fwd_w * tn);
}

extern "C" void kernel_launch(void* const* d_in, const int* in_sizes, int n_in,
                              void* d_out, int out_size, void* d_ws, size_t ws_size,
                              hipStream_t stream) {
    const float4* events = (const float4*)d_in[0];
    const int* curr_time = (const int*)d_in[1];
    const int* delta_t   = (const int*)d_in[2];
    const int* width     = (const int*)d_in[3];
    const int* height    = (const int*)d_in[4];
    float* out = (float*)d_out;
    const int n = in_sizes[0] / 4;

    // ws layout: [cursor 4KB][bucket NGRP*capg*4B][overflow list (rest)]
    int capg = 0;
    if (ws_size > CURSOR_BYTES + OF_RESERVE)
        capg = (int)(((ws_size - CURSOR_BYTES - OF_RESERVE)
                      / (NGRP * sizeof(unsigned))) & ~(size_t)15);

    if (capg >= MIN_CAPG) {
        unsigned* cursor = (unsigned*)d_ws;
        unsigned* bucket = (unsigned*)((char*)d_ws + CURSOR_BYTES);
        unsigned* oflist = bucket + (size_t)NGRP * capg;
        int ofcap = (int)((ws_size - CURSOR_BYTES
                           - (size_t)NGRP * capg * sizeof(unsigned))
                          / (2 * sizeof(unsigned)));
        hipMemsetAsync(cursor, 0, CURSOR_BYTES, stream);
        p2_bucket<<<NB2, 1024, 0, stream>>>(events, n, cursor, bucket,
                                            oflist, ofcap, capg,
                                            curr_time, delta_t);
        p3_accum<<<GH, 1024, 0, stream>>>(cursor, bucket, out, capg);
        p4_overflow<<<16, 256, 0, stream>>>(cursor, oflist, ofcap, out);
    } else {
        hipMemsetAsync(out, 0, (size_t)out_size * sizeof(float), stream);
        const int block = 256;
        const int grid  = (n + block - 1) / block;
        voxel_scatter_kernel<<<grid, block, 0, stream>>>(events, out, n,
                                                         curr_time, delta_t,
                                                         width, height);
    }
}

// Round 6
// 412.025 us; speedup vs baseline: 1.2373x; 1.0076x over previous
//
#include <hip/hip_runtime.h>
#include <hip/hip_bf16.h>

// VoxelGrid: 10M events -> (10, 720, 1280) fp32 grid, bilinear splat in time.
// R1: naive 20M device atomics -> 21 G atomics/s ceiling (958 us).
// R2-R4: row-bucket (720) p2 stuck ~190 us: partial-line L2 evictions ->
//   4-5x HBM write amplification on scattered 4B stores.
// R5: coarse buckets (240 = y/3, ylo packed in record) -> p2 < 127 us (off
//   top-5), total 415. p3 now critical: 127 us, VALU 13%, HBM 10%,
//   occupancy 66% -> latency-bound + ragged block tail (720 blocks at
//   2/CU = 512 capacity -> 208-block third wave).
// R6: p3 at 512 thr/block: 51.2 KB LDS x 3 = 153.6 <= 160 KB -> 3 blocks/CU,
//   720 = 3x240 <= 768 -> ALL p3 blocks resident, zero tail, 24 waves/CU.

#define NUM_BINS 5
#define DT_OFFSET 1
#define GW 1280
#define GH 720
#define NSLAB (NUM_BINS * 2)   // 10 (bin, polarity) slabs
#define NGRP 240               // coarse buckets (y/3)
#define NB2 256                // phase-2 blocks
#define CURSOR_BYTES 4096      // cursor[0..239] buckets, cursor[240] overflow
#define OF_RESERVE (512*1024)  // overflow list reserve at ws tail
#define MIN_CAPG 45056         // required slots/bucket (mean fill ~45.5K+15sig)

// Packed record: [q:16 | ylo:2 | pos:1 | xi:11], tn ~= q/65535, y = 3*g + ylo.
// Zero word decodes to tn=0 -> contributes +0.0 (pad slots are harmless).

// ---------------- Phase 2: bucket events by y/3 ----------------
__global__ __launch_bounds__(1024) void p2_bucket(
        const float4* __restrict__ ev, int n,
        unsigned* __restrict__ cursor, unsigned* __restrict__ bucket,
        unsigned* __restrict__ oflist, int ofcap, int capg,
        const int* __restrict__ ct_p, const int* __restrict__ dt_p) {
    __shared__ unsigned hist[NGRP];
    __shared__ unsigned base[NGRP];

    const int chunk = (n + gridDim.x - 1) / gridDim.x;
    const int start = blockIdx.x * chunk;
    const int end   = min(n, start + chunk);

    if (threadIdx.x < NGRP) hist[threadIdx.x] = 0u;
    __syncthreads();

    // pass A: per-bucket counts (reads warm L3 for pass B)
    for (int i = start + (int)threadIdx.x; i < end; i += blockDim.x) {
        int yi = (int)ev[i].z;
        atomicAdd(&hist[yi / 3], 1u);
    }
    __syncthreads();

    // reserve 64B-aligned runs; zero pad slots
    if (threadIdx.x < NGRP) {
        unsigned k = threadIdx.x;
        unsigned c = hist[k];
        if (c) {
            unsigned r = (c + 15u) & ~15u;
            unsigned b = atomicAdd(&cursor[k], r);
            base[k] = b;
            unsigned* bk = bucket + (size_t)k * capg;
            for (unsigned j = c; j < r; ++j) {
                unsigned slot = b + j;
                if (slot < (unsigned)capg) bk[slot] = 0u;
            }
        } else {
            base[k] = 0u;
        }
        hist[k] = 0u;          // becomes pass-B cursor
    }
    __syncthreads();

    const int ct  = *ct_p;
    const int dti = *dt_p;
    const float bt  = (float)(ct - dti);
    const float dtf = (float)(dti + DT_OFFSET);

    // pass B: pack + scatter (long runs keep tail lines L2-resident until
    // complete -> full-line writebacks; verified by R5 WRITE_SIZE drop)
    for (int i = start + (int)threadIdx.x; i < end; i += blockDim.x) {
        float4 e = ev[i];
        int yi  = (int)e.z;
        int xi  = (int)e.y;
        int pos = (e.w > 0.0f) ? 1 : 0;
        int g   = yi / 3;
        int ylo = yi - 3 * g;
        float tn = (e.x - bt) / dtf;               // in [0, 1)
        unsigned q = (unsigned)(tn * 65535.0f + 0.5f);
        if (q > 65535u) q = 65535u;
        unsigned word = (q << 14) | ((unsigned)ylo << 12)
                      | ((unsigned)pos << 11) | (unsigned)xi;
        unsigned j    = atomicAdd(&hist[g], 1u);
        unsigned slot = base[g] + j;
        if (slot < (unsigned)capg) {
            bucket[(size_t)g * capg + slot] = word;
        } else {
            // statistically ~never: append to overflow list, drained by p4
            unsigned k = atomicAdd(&cursor[NGRP], 1u);
            if (k < (unsigned)ofcap) {
                oflist[2 * k]     = (unsigned)yi;
                oflist[2 * k + 1] = word;
            }
        }
    }
}

// ---------------- Phase 3: per-row LDS accumulate + exclusive writeout ------
// 512 threads: 51.2 KB LDS -> 3 blocks/CU (153.6 <= 160 KB), 720 blocks all
// resident in one shot (3 x 240 <= 3 x 256), 24 waves/CU latency hiding.
__global__ __launch_bounds__(512) void p3_accum(
        const unsigned* __restrict__ cursor, const unsigned* __restrict__ bucket,
        float* __restrict__ out, int capg) {
    __shared__ float tile[NSLAB * GW];   // 51,200 B
    const int y    = blockIdx.x;
    const int g    = y / 3;
    const unsigned tgt = (unsigned)(y - 3 * g);

    for (int k = threadIdx.x; k < NSLAB * GW; k += blockDim.x) tile[k] = 0.0f;
    __syncthreads();

    unsigned cnt = cursor[g];
    if (cnt > (unsigned)capg) cnt = (unsigned)capg;   // rest went to overflow
    // cnt is a multiple of 16 (64B-aligned reservations) -> exact uint4 loop
    const uint4* bk4 = (const uint4*)(bucket + (size_t)g * capg);
    unsigned n4 = cnt / 4;

    for (unsigned j = threadIdx.x; j < n4; j += blockDim.x) {
        uint4 w4 = bk4[j];
        #pragma unroll
        for (int c = 0; c < 4; ++c) {
            unsigned w = (c == 0) ? w4.x : (c == 1) ? w4.y : (c == 2) ? w4.z : w4.w;
            if (((w >> 12) & 3u) != tgt) continue;    // other row in this bucket
            int   xi  = (int)(w & 0x7FFu);
            int   pos = (int)((w >> 11) & 1u);
            float tn  = (float)(w >> 14) * (1.0f / 65535.0f);
            float bf  = (NUM_BINS - 1.0f) * tn;
            float back = floorf(bf);
            float fw   = bf - back;
            int   b    = (int)back;
            if (b > NUM_BINS - 2) b = NUM_BINS - 2;   // safety clamp
            int   idx  = (b * 2 + pos) * GW + xi;
            atomicAdd(&tile[idx],          (1.0f - fw) * tn);   // ds_add_f32
            atomicAdd(&tile[idx + 2 * GW], fw * tn);
        }
    }
    __syncthreads();

    // exclusive coalesced float4 writeout: row y of each of the 10 slabs
    for (int k = threadIdx.x; k < NSLAB * GW / 4; k += blockDim.x) {
        int s  = k / (GW / 4);
        int x4 = k % (GW / 4);
        ((float4*)(out + ((size_t)s * GH + y) * GW))[x4] =
            ((const float4*)(tile + s * GW))[x4];
    }
}

// ---------------- Phase 4: drain overflow list (usually empty) --------------
__global__ void p4_overflow(const unsigned* __restrict__ cursor,
                            const unsigned* __restrict__ oflist, int ofcap,
                            float* __restrict__ out) {
    unsigned nof = cursor[NGRP];
    if (nof > (unsigned)ofcap) nof = (unsigned)ofcap;
    for (unsigned k = blockIdx.x * blockDim.x + threadIdx.x; k < nof;
         k += gridDim.x * blockDim.x) {
        unsigned yi = oflist[2 * k];
        unsigned w  = oflist[2 * k + 1];
        int   xi  = (int)(w & 0x7FFu);
        int   pos = (int)((w >> 11) & 1u);
        float tn  = (float)(w >> 14) * (1.0f / 65535.0f);
        float bf  = (NUM_BINS - 1.0f) * tn;
        float back = floorf(bf);
        float fw   = bf - back;
        int   b    = (int)back;
        if (b > NUM_BINS - 2) b = NUM_BINS - 2;
        atomicAdd(&out[((size_t)(b * 2 + pos) * GH + yi) * GW + xi],
                  (1.0f - fw) * tn);
        atomicAdd(&out[((size_t)((b + 1) * 2 + pos) * GH + yi) * GW + xi],
                  fw * tn);
    }
}

// ---------------- Fallback: R1 naive atomic kernel (if ws too small) --------
__global__ void voxel_scatter_kernel(const float4* __restrict__ events,
                                     float* __restrict__ out, int n,
                                     const int* __restrict__ ct_p,
                                     const int* __restrict__ dt_p,
                                     const int* __restrict__ w_p,
                                     const int* __restrict__ h_p) {
    int i = blockIdx.x * blockDim.x + threadIdx.x;
    if (i >= n) return;
    const int ct = *ct_p, dti = *dt_p, W = *w_p, H = *h_p;
    const float bt  = (float)(ct - dti);
    const float dtf = (float)(dti + DT_OFFSET);
    float4 e = events[i];
    const float tn    = (e.x - bt) / dtf;
    const float bin_f = (NUM_BINS - 1.0f) * tn;
    const float back  = floorf(bin_f);
    const float fwd_w = bin_f - back;
    const int back_i = (int)back;
    const int pos    = (e.w > 0.0f) ? 1 : 0;
    const int xi = (int)e.y, yi = (int)e.z;
    const int plane = H * W, slab = 2 * plane;
    const int base = (back_i * 2 + pos) * plane + yi * W + xi;
    atomicAdd(&out[base],        (1.0f - fwd_w) * tn);
    atomicAdd(&out[base + slab], fwd_w * tn);
}

extern "C" void kernel_launch(void* const* d_in, const int* in_sizes, int n_in,
                              void* d_out, int out_size, void* d_ws, size_t ws_size,
                              hipStream_t stream) {
    const float4* events = (const float4*)d_in[0];
    const int* curr_time = (const int*)d_in[1];
    const int* delta_t   = (const int*)d_in[2];
    const int* width     = (const int*)d_in[3];
    const int* height    = (const int*)d_in[4];
    float* out = (float*)d_out;
    const int n = in_sizes[0] / 4;

    // ws layout: [cursor 4KB][bucket NGRP*capg*4B][overflow list (rest)]
    int capg = 0;
    if (ws_size > CURSOR_BYTES + OF_RESERVE)
        capg = (int)(((ws_size - CURSOR_BYTES - OF_RESERVE)
                      / (NGRP * sizeof(unsigned))) & ~(size_t)15);

    if (capg >= MIN_CAPG) {
        unsigned* cursor = (unsigned*)d_ws;
        unsigned* bucket = (unsigned*)((char*)d_ws + CURSOR_BYTES);
        unsigned* oflist = bucket + (size_t)NGRP * capg;
        int ofcap = (int)((ws_size - CURSOR_BYTES
                           - (size_t)NGRP * capg * sizeof(unsigned))
                          / (2 * sizeof(unsigned)));
        hipMemsetAsync(cursor, 0, CURSOR_BYTES, stream);
        p2_bucket<<<NB2, 1024, 0, stream>>>(events, n, cursor, bucket,
                                            oflist, ofcap, capg,
                                            curr_time, delta_t);
        p3_accum<<<GH, 512, 0, stream>>>(cursor, bucket, out, capg);
        p4_overflow<<<16, 256, 0, stream>>>(cursor, oflist, ofcap, out);
    } else {
        hipMemsetAsync(out, 0, (size_t)out_size * sizeof(float), stream);
        const int block = 256;
        const int grid  = (n + block - 1) / block;
        voxel_scatter_kernel<<<grid, block, 0, stream>>>(events, out, n,
                                                         curr_time, delta_t,
                                                         width, height);
    }
}

// Round 7
// 401.032 us; speedup vs baseline: 1.2712x; 1.0274x over previous
//
#include <hip/hip_runtime.h>
#include <hip/hip_bf16.h>

// VoxelGrid: 10M events -> (10, 720, 1280) fp32 grid, bilinear splat in time.
// R1: naive 20M device atomics -> 21 G atomics/s (958 us).
// R2-R4: 720-bucket sort: partial-line L2 evictions -> 4-5x write amp, ~190 us.
// R5: 240 coarse buckets (y/3) -> p2 write amp fixed (62 MB), total 415.
// R6: p3 residency fix neutral -> p3 not wave-latency bound. Both kernels are
//   bound by serialized small work: p2 re-reads+re-decodes events in pass B;
//   p3 decodes every record 3x (3 row-blocks/bucket) and its two LDS atomics
//   always collide on one bank (stride 2560 % 32 == 0).
// R7: p2 keeps its 40 events/thread in unrolled REGISTER arrays (single read);
//   p3 = one block per bucket (240 x 1024, 154 KB LDS tile for 3 rows x 10
//   slabs, +4 pad stride -> atomic pair 24 banks apart), decode-once.

#define NUM_BINS 5
#define DT_OFFSET 1
#define GW 1280
#define GH 720
#define NSLAB (NUM_BINS * 2)   // 10 (bin, polarity) slabs
#define NGRP 240               // coarse buckets (y/3)
#define NB2 256                // phase-2 blocks
#define ITERS 40               // events per thread in p2 (256*1024*40 >= 10M)
#define GWP (GW + 4)           // padded x-stride in p3 tile (bank spacing)
#define CURSOR_BYTES 4096      // cursor[0..239] buckets, cursor[240] overflow
#define OF_RESERVE (512*1024)  // overflow list reserve at ws tail
#define MIN_CAPG 45056         // slots/bucket (mean ~43.7K incl pad, +6 sigma)

// Packed record: [q:16 | ylo:2 | pos:1 | xi:11], tn ~= q/65535, y = 3*g + ylo.
// Zero word decodes to tn=0 -> contributes +0.0 (pad slots are harmless).

// ---------------- Phase 2: bucket events by y/3 (single global read) --------
__global__ __launch_bounds__(1024) void p2_bucket(
        const float4* __restrict__ ev, int n,
        unsigned* __restrict__ cursor, unsigned* __restrict__ bucket,
        unsigned* __restrict__ oflist, int ofcap, int capg,
        const int* __restrict__ ct_p, const int* __restrict__ dt_p) {
    __shared__ unsigned hist[NGRP];
    __shared__ unsigned base[NGRP];

    const int chunk = (n + gridDim.x - 1) / gridDim.x;
    const int start = blockIdx.x * chunk;
    const int end   = min(n, start + chunk);

    if (threadIdx.x < NGRP) hist[threadIdx.x] = 0u;
    __syncthreads();

    const int ct  = *ct_p;
    const int dti = *dt_p;
    const float bt  = (float)(ct - dti);
    const float dtf = (float)(dti + DT_OFFSET);

    // pass A: coalesced float4 read, decode into REGISTER arrays, count hist
    unsigned wk[ITERS];   // packed record
    int      gk[ITERS];   // bucket id, -1 = invalid
    #pragma unroll
    for (int k = 0; k < ITERS; ++k) {
        int i = start + (int)threadIdx.x + k * 1024;
        gk[k] = -1;
        wk[k] = 0u;
        if (i < end) {
            float4 e = ev[i];
            int yi  = (int)e.z;
            int xi  = (int)e.y;
            int pos = (e.w > 0.0f) ? 1 : 0;
            int g   = yi / 3;
            int ylo = yi - 3 * g;
            float tn = (e.x - bt) / dtf;           // in [0, 1)
            unsigned q = (unsigned)(tn * 65535.0f + 0.5f);
            if (q > 65535u) q = 65535u;
            wk[k] = (q << 14) | ((unsigned)ylo << 12)
                  | ((unsigned)pos << 11) | (unsigned)xi;
            gk[k] = g;
            atomicAdd(&hist[g], 1u);
        }
    }
    __syncthreads();

    // reserve 64B-aligned runs in the global bucket; zero pad slots
    if (threadIdx.x < NGRP) {
        unsigned k = threadIdx.x;
        unsigned c = hist[k];
        if (c) {
            unsigned r = (c + 15u) & ~15u;
            unsigned b = atomicAdd(&cursor[k], r);
            base[k] = b;
            unsigned* bk = bucket + (size_t)k * capg;
            for (unsigned j = c; j < r; ++j) {
                unsigned slot = b + j;
                if (slot < (unsigned)capg) bk[slot] = 0u;
            }
        } else {
            base[k] = 0u;
        }
        hist[k] = 0u;          // becomes pass-B cursor
    }
    __syncthreads();

    // pass B: scatter straight from registers (no re-read, no re-decode)
    #pragma unroll
    for (int k = 0; k < ITERS; ++k) {
        if (gk[k] >= 0) {
            int g = gk[k];
            unsigned j    = atomicAdd(&hist[g], 1u);
            unsigned slot = base[g] + j;
            if (slot < (unsigned)capg) {
                bucket[(size_t)g * capg + slot] = wk[k];
            } else {
                unsigned o = atomicAdd(&cursor[NGRP], 1u);
                if (o < (unsigned)ofcap) {
                    oflist[2 * o]     = (unsigned)(3 * g + ((wk[k] >> 12) & 3u));
                    oflist[2 * o + 1] = wk[k];
                }
            }
        }
    }
}

// ---------------- Phase 3: one block per bucket, decode-once ----------------
// Tile: [slab 0..9][ylo 0..2][x 0..GW) with padded stride GWP.
// Atomic pair offsets differ by 6*GWP dwords -> 24 banks apart (was 0).
__global__ __launch_bounds__(1024) void p3_accum(
        const unsigned* __restrict__ cursor, const unsigned* __restrict__ bucket,
        float* __restrict__ out, int capg) {
    __shared__ float tile[NSLAB * 3 * GWP];   // 154,080 B (<= 160 KiB)
    const int g = blockIdx.x;

    for (int k = threadIdx.x; k < NSLAB * 3 * GWP; k += blockDim.x)
        tile[k] = 0.0f;
    __syncthreads();

    unsigned cnt = cursor[g];
    if (cnt > (unsigned)capg) cnt = (unsigned)capg;   // rest went to overflow
    const uint4* bk4 = (const uint4*)(bucket + (size_t)g * capg);
    unsigned n4 = cnt / 4;                            // cnt is multiple of 16

    for (unsigned j = threadIdx.x; j < n4; j += blockDim.x) {
        uint4 w4 = bk4[j];
        #pragma unroll
        for (int c = 0; c < 4; ++c) {
            unsigned w = (c == 0) ? w4.x : (c == 1) ? w4.y : (c == 2) ? w4.z : w4.w;
            int   xi  = (int)(w & 0x7FFu);
            int   pos = (int)((w >> 11) & 1u);
            int   ylo = (int)((w >> 12) & 3u);
            float tn  = (float)(w >> 14) * (1.0f / 65535.0f);
            float bf  = (NUM_BINS - 1.0f) * tn;
            float back = floorf(bf);
            float fw   = bf - back;
            int   b    = (int)back;
            if (b > NUM_BINS - 2) b = NUM_BINS - 2;   // safety clamp
            int   idx  = ((b * 2 + pos) * 3 + ylo) * GWP + xi;
            atomicAdd(&tile[idx],           (1.0f - fw) * tn);  // ds_add_f32
            atomicAdd(&tile[idx + 6 * GWP], fw * tn);
        }
    }
    __syncthreads();

    // exclusive coalesced float4 writeout: 3 rows x 10 slabs
    // (row base offset (s*3+ylo)*GWP dwords; GWP*4 % 16 == 0 -> aligned)
    for (int k = threadIdx.x; k < NSLAB * 3 * (GW / 4); k += blockDim.x) {
        int r  = k / (GW / 4);        // 0..29 = s*3 + ylo
        int x4 = k % (GW / 4);
        int s  = r / 3;
        int ylo = r - 3 * s;
        int y  = 3 * g + ylo;
        ((float4*)(out + ((size_t)s * GH + y) * GW))[x4] =
            ((const float4*)(tile + r * GWP))[x4];
    }
}

// ---------------- Phase 4: drain overflow list (usually empty) --------------
__global__ void p4_overflow(const unsigned* __restrict__ cursor,
                            const unsigned* __restrict__ oflist, int ofcap,
                            float* __restrict__ out) {
    unsigned nof = cursor[NGRP];
    if (nof > (unsigned)ofcap) nof = (unsigned)ofcap;
    for (unsigned k = blockIdx.x * blockDim.x + threadIdx.x; k < nof;
         k += gridDim.x * blockDim.x) {
        unsigned yi = oflist[2 * k];
        unsigned w  = oflist[2 * k + 1];
        int   xi  = (int)(w & 0x7FFu);
        int   pos = (int)((w >> 11) & 1u);
        float tn  = (float)(w >> 14) * (1.0f / 65535.0f);
        float bf  = (NUM_BINS - 1.0f) * tn;
        float back = floorf(bf);
        float fw   = bf - back;
        int   b    = (int)back;
        if (b > NUM_BINS - 2) b = NUM_BINS - 2;
        atomicAdd(&out[((size_t)(b * 2 + pos) * GH + yi) * GW + xi],
                  (1.0f - fw) * tn);
        atomicAdd(&out[((size_t)((b + 1) * 2 + pos) * GH + yi) * GW + xi],
                  fw * tn);
    }
}

// ---------------- Fallback: R1 naive atomic kernel (if ws too small) --------
__global__ void voxel_scatter_kernel(const float4* __restrict__ events,
                                     float* __restrict__ out, int n,
                                     const int* __restrict__ ct_p,
                                     const int* __restrict__ dt_p,
                                     const int* __restrict__ w_p,
                                     const int* __restrict__ h_p) {
    int i = blockIdx.x * blockDim.x + threadIdx.x;
    if (i >= n) return;
    const int ct = *ct_p, dti = *dt_p, W = *w_p, H = *h_p;
    const float bt  = (float)(ct - dti);
    const float dtf = (float)(dti + DT_OFFSET);
    float4 e = events[i];
    const float tn    = (e.x - bt) / dtf;
    const float bin_f = (NUM_BINS - 1.0f) * tn;
    const float back  = floorf(bin_f);
    const float fwd_w = bin_f - back;
    const int back_i = (int)back;
    const int pos    = (e.w > 0.0f) ? 1 : 0;
    const int xi = (int)e.y, yi = (int)e.z;
    const int plane = H * W, slab = 2 * plane;
    const int base = (back_i * 2 + pos) * plane + yi * W + xi;
    atomicAdd(&out[base],        (1.0f - fwd_w) * tn);
    atomicAdd(&out[base + slab], fwd_w * tn);
}

extern "C" void kernel_launch(void* const* d_in, const int* in_sizes, int n_in,
                              void* d_out, int out_size, void* d_ws, size_t ws_size,
                              hipStream_t stream) {
    const float4* events = (const float4*)d_in[0];
    const int* curr_time = (const int*)d_in[1];
    const int* delta_t   = (const int*)d_in[2];
    const int* width     = (const int*)d_in[3];
    const int* height    = (const int*)d_in[4];
    float* out = (float*)d_out;
    const int n = in_sizes[0] / 4;

    // ws layout: [cursor 4KB][bucket NGRP*capg*4B][overflow list (rest)]
    int capg = 0;
    if (ws_size > CURSOR_BYTES + OF_RESERVE)
        capg = (int)(((ws_size - CURSOR_BYTES - OF_RESERVE)
                      / (NGRP * sizeof(unsigned))) & ~(size_t)15);

    if (capg >= MIN_CAPG && n <= NB2 * 1024 * ITERS) {
        unsigned* cursor = (unsigned*)d_ws;
        unsigned* bucket = (unsigned*)((char*)d_ws + CURSOR_BYTES);
        unsigned* oflist = bucket + (size_t)NGRP * capg;
        int ofcap = (int)((ws_size - CURSOR_BYTES
                           - (size_t)NGRP * capg * sizeof(unsigned))
                          / (2 * sizeof(unsigned)));
        hipMemsetAsync(cursor, 0, CURSOR_BYTES, stream);
        p2_bucket<<<NB2, 1024, 0, stream>>>(events, n, cursor, bucket,
                                            oflist, ofcap, capg,
                                            curr_time, delta_t);
        p3_accum<<<NGRP, 1024, 0, stream>>>(cursor, bucket, out, capg);
        p4_overflow<<<16, 256, 0, stream>>>(cursor, oflist, ofcap, out);
    } else {
        hipMemsetAsync(out, 0, (size_t)out_size * sizeof(float), stream);
        const int block = 256;
        const int grid  = (n + block - 1) / block;
        voxel_scatter_kernel<<<grid, block, 0, stream>>>(events, out, n,
                                                         curr_time, delta_t,
                                                         width, height);
    }
}